// Round 1
// baseline (1543.219 us; speedup 1.0000x reference)
//
#include <hip/hip_runtime.h>
#include <math.h>

#define KSIZE 5
#define KTOT 125

static constexpr float LOWER_CURV = -0.22703196f;
static constexpr float UPPER_CURV = 0.36853024f;

__global__ void transform_kernel(const float* __restrict__ x,
                                 float* __restrict__ h, int n) {
    int i = blockIdx.x * blockDim.x + threadIdx.x;
    if (i < n) {
        float t = (x[i] - LOWER_CURV) / (UPPER_CURV - LOWER_CURV) * 20.0f - 10.0f;
        h[i] = fminf(fmaxf(t, -10.0f), 10.0f);
    }
}

// out[v,o] = bias[o] + sum_i h[v,i] * root[i,o]
template<int Cin, int Cout>
__global__ void root_kernel(const float* __restrict__ h,
                            const float* __restrict__ root,
                            const float* __restrict__ bias,
                            float* __restrict__ out, int n) {
    int idx = blockIdx.x * blockDim.x + threadIdx.x;
    if (idx >= n * Cout) return;
    int v = idx / Cout, o = idx % Cout;
    float acc = bias[o];
#pragma unroll
    for (int i = 0; i < Cin; ++i)
        acc += h[v * Cin + i] * root[i * Cout + o];
    out[idx] = acc;
}

// Per-edge: recompute 8 spline taps, accumulate 8 small matvecs in registers,
// one atomicAdd per output channel.
template<int Cin, int Cout>
__global__ void edge_kernel(const float* __restrict__ h,
                            const int* __restrict__ src,
                            const int* __restrict__ dst,
                            const float* __restrict__ attr,
                            const float* __restrict__ W,
                            float* __restrict__ out, int E) {
    int e = blockIdx.x * blockDim.x + threadIdx.x;
    if (e >= E) return;
    int s = src[e], d = dst[e];

    float fr[3];
    int   k0[3];
#pragma unroll
    for (int dd = 0; dd < 3; ++dd) {
        float p = attr[e * 3 + dd];
        p = fminf(fmaxf(p, 0.0f), 1.0f) * (float)(KSIZE - 1);
        float f0 = floorf(p);
        f0 = fminf(f0, (float)(KSIZE - 2));   // p >= 0 so floor >= 0 already
        k0[dd] = (int)f0;
        fr[dd] = p - f0;
    }

    float xs[Cin];
#pragma unroll
    for (int i = 0; i < Cin; ++i) xs[i] = h[s * Cin + i];

    float acc[Cout];
#pragma unroll
    for (int o = 0; o < Cout; ++o) acc[o] = 0.0f;

#pragma unroll
    for (int t = 0; t < 8; ++t) {
        const int b0 = t & 1, b1 = (t >> 1) & 1, b2 = (t >> 2) & 1;
        float bs = (b0 ? fr[0] : 1.0f - fr[0]) *
                   (b1 ? fr[1] : 1.0f - fr[1]) *
                   (b2 ? fr[2] : 1.0f - fr[2]);
        int wi = (k0[0] + b0) * 25 + (k0[1] + b1) * 5 + (k0[2] + b2);
        const float* __restrict__ Wp = W + wi * (Cin * Cout);
#pragma unroll
        for (int i = 0; i < Cin; ++i) {
            float xv = bs * xs[i];
#pragma unroll
            for (int o = 0; o < Cout; ++o)
                acc[o] += xv * __ldg(&Wp[i * Cout + o]);
        }
    }

#pragma unroll
    for (int o = 0; o < Cout; ++o)
        atomicAdd(&out[d * Cout + o], acc[o]);
}

__global__ void elu_kernel(float* __restrict__ h, int n) {
    int i = blockIdx.x * blockDim.x + threadIdx.x;
    if (i < n) {
        float v = h[i];
        h[i] = v > 0.0f ? v : expm1f(v);
    }
}

static inline int cdiv(int a, int b) { return (a + b - 1) / b; }

template<int Cin, int Cout>
static void run_layer(const float* hin, float* hout,
                      const int* src, const int* dst, const float* attr,
                      const float* W, const float* root, const float* bias,
                      int N, int E, hipStream_t stream) {
    const int B = 256;
    root_kernel<Cin, Cout><<<cdiv(N * Cout, B), B, 0, stream>>>(hin, root, bias, hout, N);
    edge_kernel<Cin, Cout><<<cdiv(E, B), B, 0, stream>>>(hin, src, dst, attr, W, hout, E);
    elu_kernel<<<cdiv(N * Cout, B), B, 0, stream>>>(hout, N * Cout);
}

extern "C" void kernel_launch(void* const* d_in, const int* in_sizes, int n_in,
                              void* d_out, int out_size, void* d_ws, size_t ws_size,
                              hipStream_t stream) {
    const float* x    = (const float*)d_in[0];
    const int*   ei   = (const int*)d_in[1];
    const float* attr = (const float*)d_in[2];
    const float* w1 = (const float*)d_in[3],  *r1 = (const float*)d_in[4],  *b1 = (const float*)d_in[5];
    const float* w2 = (const float*)d_in[6],  *r2 = (const float*)d_in[7],  *b2 = (const float*)d_in[8];
    const float* w3 = (const float*)d_in[9],  *r3 = (const float*)d_in[10], *b3 = (const float*)d_in[11];
    const float* w4 = (const float*)d_in[12], *r4 = (const float*)d_in[13], *b4 = (const float*)d_in[14];
    const float* w5 = (const float*)d_in[15], *r5 = (const float*)d_in[16], *b5 = (const float*)d_in[17];

    const int N = in_sizes[0];      // 50000 (x is [N,1])
    const int E = in_sizes[1] / 2;  // 400000
    const int* src = ei;
    const int* dst = ei + E;

    float* bufA = (float*)d_ws;
    float* bufB = bufA + (size_t)N * 16;
    float* outF = (float*)d_out;

    const int B = 256;
    transform_kernel<<<cdiv(N, B), B, 0, stream>>>(x, bufA, N);

    run_layer<1, 8 >(bufA, bufB, src, dst, attr, w1, r1, b1, N, E, stream);
    run_layer<8, 16>(bufB, bufA, src, dst, attr, w2, r2, b2, N, E, stream);
    run_layer<16,16>(bufA, bufB, src, dst, attr, w3, r3, b3, N, E, stream);
    run_layer<16,8 >(bufB, bufA, src, dst, attr, w4, r4, b4, N, E, stream);
    run_layer<8, 1 >(bufA, outF, src, dst, attr, w5, r5, b5, N, E, stream);
}

// Round 2
// 667.985 us; speedup vs baseline: 2.3103x; 2.3103x over previous
//
#include <hip/hip_runtime.h>
#include <math.h>

#define KSIZE 5
#define KTOT 125

static constexpr float LOWER_CURV = -0.22703196f;
static constexpr float UPPER_CURV = 0.36853024f;

__device__ __constant__ int TAPOFF[8] = {0, 25, 5, 30, 1, 26, 6, 31};

static inline int cdiv(int a, int b) { return (a + b - 1) / b; }

// ---------- small utility kernels ----------

__global__ void transform_kernel(const float* __restrict__ x,
                                 float* __restrict__ h, int n) {
    int i = blockIdx.x * blockDim.x + threadIdx.x;
    if (i < n) {
        float t = (x[i] - LOWER_CURV) / (UPPER_CURV - LOWER_CURV) * 20.0f - 10.0f;
        h[i] = fminf(fmaxf(t, -10.0f), 10.0f);
    }
}

__global__ void zero_int(int* __restrict__ p, int n) {
    int i = blockIdx.x * blockDim.x + threadIdx.x;
    if (i < n) p[i] = 0;
}

__global__ void hist_kernel(const int* __restrict__ dst, int* __restrict__ counts, int E) {
    int e = blockIdx.x * blockDim.x + threadIdx.x;
    if (e < E) atomicAdd(&counts[dst[e]], 1);
}

// block-level exclusive scan (256 threads), writes per-block exclusive values + block sums
__global__ void scan_blocks(const int* __restrict__ counts, int* __restrict__ rowptr,
                            int* __restrict__ bsums, int n) {
    __shared__ int sh[256];
    int tid = threadIdx.x;
    int i = blockIdx.x * 256 + tid;
    int v = (i < n) ? counts[i] : 0;
    sh[tid] = v;
    __syncthreads();
    for (int off = 1; off < 256; off <<= 1) {
        int t = (tid >= off) ? sh[tid - off] : 0;
        __syncthreads();
        sh[tid] += t;
        __syncthreads();
    }
    if (i < n) rowptr[i] = sh[tid] - v;          // exclusive within block
    if (tid == 255) bsums[blockIdx.x] = sh[255]; // block total
}

// single-block exclusive scan of block sums (nb <= 256)
__global__ void scan_sums(int* __restrict__ bsums, int nb) {
    __shared__ int sh[256];
    int tid = threadIdx.x;
    int v = (tid < nb) ? bsums[tid] : 0;
    sh[tid] = v;
    __syncthreads();
    for (int off = 1; off < 256; off <<= 1) {
        int t = (tid >= off) ? sh[tid - off] : 0;
        __syncthreads();
        sh[tid] += t;
        __syncthreads();
    }
    if (tid < nb) bsums[tid] = sh[tid] - v;      // exclusive
}

__global__ void add_offsets(int* __restrict__ rowptr, const int* __restrict__ bsums,
                            int* __restrict__ cursor, int n, int E) {
    int i = blockIdx.x * 256 + threadIdx.x;
    if (i < n) {
        int r = rowptr[i] + bsums[blockIdx.x];
        rowptr[i] = r;
        cursor[i] = r;
    }
    if (i == 0) rowptr[n] = E;
}

// scatter edges into CSR order; precompute wi-base and 8 basis weights
__global__ void build_edges(const int* __restrict__ src, const int* __restrict__ dst,
                            const float* __restrict__ attr, int* __restrict__ cursor,
                            int* __restrict__ esrc, int* __restrict__ ewib,
                            float* __restrict__ ebasis, int E) {
    int e = blockIdx.x * blockDim.x + threadIdx.x;
    if (e >= E) return;
    int d = dst[e];
    int pos = atomicAdd(&cursor[d], 1);

    float fr[3]; int k0[3];
#pragma unroll
    for (int dd = 0; dd < 3; ++dd) {
        float p = attr[e * 3 + dd];
        p = fminf(fmaxf(p, 0.0f), 1.0f) * (float)(KSIZE - 1);
        float f0 = floorf(p);
        f0 = fminf(f0, (float)(KSIZE - 2));
        k0[dd] = (int)f0;
        fr[dd] = p - f0;
    }
    esrc[pos] = src[e];
    ewib[pos] = k0[0] * 25 + k0[1] * 5 + k0[2];

    float b[8];
#pragma unroll
    for (int t = 0; t < 8; ++t) {
        float bs = ((t & 1) ? fr[0] : 1.0f - fr[0]) *
                   (((t >> 1) & 1) ? fr[1] : 1.0f - fr[1]) *
                   (((t >> 2) & 1) ? fr[2] : 1.0f - fr[2]);
        b[t] = bs;
    }
    float4* bp = (float4*)(ebasis + (size_t)pos * 8);
    bp[0] = make_float4(b[0], b[1], b[2], b[3]);
    bp[1] = make_float4(b[4], b[5], b[6], b[7]);
}

// Wt[wi][o][i] = W[wi][i][o]
__global__ void transpose_w(const float* __restrict__ W, float* __restrict__ Wt,
                            int Cin, int Cout) {
    int idx = blockIdx.x * blockDim.x + threadIdx.x;
    int tot = KTOT * Cin * Cout;
    if (idx >= tot) return;
    int wi = idx / (Cin * Cout);
    int r = idx % (Cin * Cout);
    int i = r / Cout, o = r % Cout;
    Wt[(wi * Cout + o) * Cin + i] = W[idx];
}

// ---------- fused per-layer gather kernel ----------
// Cout lanes per node (LPG). Each lane owns one output channel; loops over
// the node's CSR edge list, register-accumulates, adds root+bias, ELU, one write.
template<int Cin, int Cout>
__global__ void agg_kernel(const int* __restrict__ rowptr,
                           const int* __restrict__ esrc,
                           const int* __restrict__ ewib,
                           const float* __restrict__ ebasis,
                           const float* __restrict__ x,
                           const float* __restrict__ Wt,   // [125][Cout][Cin]
                           const float* __restrict__ root, // [Cin][Cout]
                           const float* __restrict__ bias, // [Cout]
                           float* __restrict__ out,        // [N][Cout]
                           int N) {
    constexpr int LPG = (Cout >= 8) ? Cout : 8;
    int t = blockIdx.x * blockDim.x + threadIdx.x;
    int v = t / LPG;
    int lane = t % LPG;
    if (v >= N) return;

    int beg = rowptr[v], end = rowptr[v + 1];

    if constexpr (Cout == 1) {
        // lane = input channel i (Cin == 8)
        float acc = 0.0f;
        for (int p = beg; p < end; ++p) {
            int s = esrc[p];
            int wib = ewib[p];
            float xv = x[s * Cin + lane];
            const float4* bp = (const float4*)(ebasis + (size_t)p * 8);
            float4 b0 = bp[0], b1 = bp[1];
            float bb[8] = {b0.x, b0.y, b0.z, b0.w, b1.x, b1.y, b1.z, b1.w};
#pragma unroll
            for (int tt = 0; tt < 8; ++tt) {
                int wi = wib + TAPOFF[tt];
                acc += bb[tt] * xv * __ldg(&Wt[wi * Cin + lane]);
            }
        }
        // root term folds into the same reduction
        acc += x[v * Cin + lane] * root[lane];
        acc += __shfl_xor(acc, 1);
        acc += __shfl_xor(acc, 2);
        acc += __shfl_xor(acc, 4);
        if (lane == 0) {
            float o = acc + bias[0];
            out[v] = o > 0.0f ? o : expm1f(o);
        }
    } else {
        float acc = 0.0f;
        for (int p = beg; p < end; ++p) {
            int s = esrc[p];
            int wib = ewib[p];
            float xs[Cin];
            if constexpr (Cin == 1) {
                xs[0] = x[s];
            } else {
                const float4* xp = (const float4*)(x + (size_t)s * Cin);
#pragma unroll
                for (int c = 0; c < Cin / 4; ++c) {
                    float4 q = xp[c];
                    xs[4 * c + 0] = q.x; xs[4 * c + 1] = q.y;
                    xs[4 * c + 2] = q.z; xs[4 * c + 3] = q.w;
                }
            }
            const float4* bp = (const float4*)(ebasis + (size_t)p * 8);
            float4 b0 = bp[0], b1 = bp[1];
            float bb[8] = {b0.x, b0.y, b0.z, b0.w, b1.x, b1.y, b1.z, b1.w};
#pragma unroll
            for (int tt = 0; tt < 8; ++tt) {
                int wi = wib + TAPOFF[tt];
                const float* wp = Wt + ((size_t)wi * Cout + lane) * Cin;
                float dot = 0.0f;
                if constexpr (Cin == 1) {
                    dot = xs[0] * __ldg(wp);
                } else {
                    const float4* wq = (const float4*)wp;
#pragma unroll
                    for (int c = 0; c < Cin / 4; ++c) {
                        float4 w4 = __ldg(&wq[c]);
                        dot += xs[4 * c + 0] * w4.x + xs[4 * c + 1] * w4.y +
                               xs[4 * c + 2] * w4.z + xs[4 * c + 3] * w4.w;
                    }
                }
                acc += bb[tt] * dot;
            }
        }
        // root + bias + ELU
        float r = bias[lane];
#pragma unroll
        for (int i = 0; i < Cin; ++i)
            r += x[(size_t)v * Cin + i] * root[i * Cout + lane];
        float o = acc + r;
        out[(size_t)v * Cout + lane] = o > 0.0f ? o : expm1f(o);
    }
}

// ---------- host ----------

template<int Cin, int Cout>
static void run_layer(const float* hin, float* hout,
                      const int* rowptr, const int* esrc, const int* ewib,
                      const float* ebasis, const float* Wt,
                      const float* root, const float* bias,
                      int N, hipStream_t stream) {
    constexpr int LPG = (Cout >= 8) ? Cout : 8;
    const int B = 256;
    agg_kernel<Cin, Cout><<<cdiv(N * LPG, B), B, 0, stream>>>(
        rowptr, esrc, ewib, ebasis, hin, Wt, root, bias, hout, N);
}

extern "C" void kernel_launch(void* const* d_in, const int* in_sizes, int n_in,
                              void* d_out, int out_size, void* d_ws, size_t ws_size,
                              hipStream_t stream) {
    const float* x    = (const float*)d_in[0];
    const int*   ei   = (const int*)d_in[1];
    const float* attr = (const float*)d_in[2];
    const float* w[5]    = {(const float*)d_in[3],  (const float*)d_in[6],
                            (const float*)d_in[9],  (const float*)d_in[12],
                            (const float*)d_in[15]};
    const float* root[5] = {(const float*)d_in[4],  (const float*)d_in[7],
                            (const float*)d_in[10], (const float*)d_in[13],
                            (const float*)d_in[16]};
    const float* bias[5] = {(const float*)d_in[5],  (const float*)d_in[8],
                            (const float*)d_in[11], (const float*)d_in[14],
                            (const float*)d_in[17]};

    const int N = in_sizes[0];
    const int E = in_sizes[1] / 2;
    const int* src = ei;
    const int* dst = ei + E;

    // ---- workspace layout (floats/ints) ----
    char* ws = (char*)d_ws;
    float* bufA   = (float*)ws;                 ws += (size_t)N * 16 * 4;
    float* bufB   = (float*)ws;                 ws += (size_t)N * 16 * 4;
    int*   counts = (int*)ws;                   ws += (size_t)N * 4;
    int*   cursor = (int*)ws;                   ws += (size_t)N * 4;
    int*   rowptr = (int*)ws;                   ws += (size_t)(N + 1) * 4;
    int*   bsums  = (int*)ws;                   ws += 256 * 4;
    int*   esrc   = (int*)ws;                   ws += (size_t)E * 4;
    int*   ewib   = (int*)ws;                   ws += (size_t)E * 4;
    float* ebasis = (float*)ws;                 ws += (size_t)E * 8 * 4;
    float* wt[5];
    const int cins[5]  = {1, 8, 16, 16, 8};
    const int couts[5] = {8, 16, 16, 8, 1};
    for (int l = 0; l < 5; ++l) {
        wt[l] = (float*)ws;
        ws += (size_t)KTOT * cins[l] * couts[l] * 4;
    }

    const int B = 256;
    const int nb = cdiv(N, 256);   // 196 blocks for N=50000 (<=256)

    // ---- CSR build ----
    zero_int<<<cdiv(N, B), B, 0, stream>>>(counts, N);
    hist_kernel<<<cdiv(E, B), B, 0, stream>>>(dst, counts, E);
    scan_blocks<<<nb, 256, 0, stream>>>(counts, rowptr, bsums, N);
    scan_sums<<<1, 256, 0, stream>>>(bsums, nb);
    add_offsets<<<nb, 256, 0, stream>>>(rowptr, bsums, cursor, N, E);
    build_edges<<<cdiv(E, B), B, 0, stream>>>(src, dst, attr, cursor,
                                              esrc, ewib, ebasis, E);

    // ---- weight transposes ----
    for (int l = 0; l < 5; ++l) {
        int tot = KTOT * cins[l] * couts[l];
        transpose_w<<<cdiv(tot, B), B, 0, stream>>>(w[l], wt[l], cins[l], couts[l]);
    }

    // ---- transform + 5 layers ----
    transform_kernel<<<cdiv(N, B), B, 0, stream>>>(x, bufA, N);

    run_layer<1, 8 >(bufA, bufB, rowptr, esrc, ewib, ebasis, wt[0], root[0], bias[0], N, stream);
    run_layer<8, 16>(bufB, bufA, rowptr, esrc, ewib, ebasis, wt[1], root[1], bias[1], N, stream);
    run_layer<16,16>(bufA, bufB, rowptr, esrc, ewib, ebasis, wt[2], root[2], bias[2], N, stream);
    run_layer<16,8 >(bufB, bufA, rowptr, esrc, ewib, ebasis, wt[3], root[3], bias[3], N, stream);
    run_layer<8, 1 >(bufA, (float*)d_out, rowptr, esrc, ewib, ebasis, wt[4], root[4], bias[4], N, stream);
}

// Round 4
// 275.325 us; speedup vs baseline: 5.6051x; 2.4262x over previous
//
#include <hip/hip_runtime.h>
#include <math.h>

#define KSIZE 5
#define KTOT 125

static constexpr float LOWER_CURV = -0.22703196f;
static constexpr float UPPER_CURV = 0.36853024f;

typedef _Float16 h2 __attribute__((ext_vector_type(2)));

__device__ __forceinline__ h2 pack_f16(float a, float b) {
    return __builtin_bit_cast(h2, __builtin_amdgcn_cvt_pkrtz(a, b));
}

__device__ __forceinline__ float fdot2f(h2 a, h2 b, float c) {
#if __has_builtin(__builtin_amdgcn_fdot2)
    return __builtin_amdgcn_fdot2(a, b, c, false);
#else
    return c + (float)a[0] * (float)b[0] + (float)a[1] * (float)b[1];
#endif
}

static inline int cdiv(int a, int b) { return (a + b - 1) / b; }

// ---------- utility kernels ----------

__global__ void transform_kernel(const float* __restrict__ x,
                                 float* __restrict__ h, int n) {
    int i = blockIdx.x * blockDim.x + threadIdx.x;
    if (i < n) {
        float t = (x[i] - LOWER_CURV) / (UPPER_CURV - LOWER_CURV) * 20.0f - 10.0f;
        h[i] = fminf(fmaxf(t, -10.0f), 10.0f);
    }
}

__global__ void zero_int(int* __restrict__ p, int n) {
    int i = blockIdx.x * blockDim.x + threadIdx.x;
    if (i < n) p[i] = 0;
}

__global__ void hist_kernel(const int* __restrict__ dst, int* __restrict__ counts, int E) {
    int e = blockIdx.x * blockDim.x + threadIdx.x;
    if (e < E) atomicAdd(&counts[dst[e]], 1);
}

__global__ void scan_blocks(const int* __restrict__ counts, int* __restrict__ rowptr,
                            int* __restrict__ bsums, int n) {
    __shared__ int sh[256];
    int tid = threadIdx.x;
    int i = blockIdx.x * 256 + tid;
    int v = (i < n) ? counts[i] : 0;
    sh[tid] = v;
    __syncthreads();
    for (int off = 1; off < 256; off <<= 1) {
        int t = (tid >= off) ? sh[tid - off] : 0;
        __syncthreads();
        sh[tid] += t;
        __syncthreads();
    }
    if (i < n) rowptr[i] = sh[tid] - v;
    if (tid == 255) bsums[blockIdx.x] = sh[255];
}

__global__ void scan_sums(int* __restrict__ bsums, int nb) {
    __shared__ int sh[256];
    int tid = threadIdx.x;
    int v = (tid < nb) ? bsums[tid] : 0;
    sh[tid] = v;
    __syncthreads();
    for (int off = 1; off < 256; off <<= 1) {
        int t = (tid >= off) ? sh[tid - off] : 0;
        __syncthreads();
        sh[tid] += t;
        __syncthreads();
    }
    if (tid < nb) bsums[tid] = sh[tid] - v;
}

__global__ void add_offsets(int* __restrict__ rowptr, const int* __restrict__ bsums,
                            int* __restrict__ cursor, int n, int E) {
    int i = blockIdx.x * 256 + threadIdx.x;
    if (i < n) {
        int r = rowptr[i] + bsums[blockIdx.x];
        rowptr[i] = r;
        cursor[i] = r;
    }
    if (i == 0) rowptr[n] = E;
}

__global__ void build_edges(const int* __restrict__ src, const int* __restrict__ dst,
                            const float* __restrict__ attr, int* __restrict__ cursor,
                            int* __restrict__ esrc, int* __restrict__ ewib,
                            float* __restrict__ ebasis, int E) {
    int e = blockIdx.x * blockDim.x + threadIdx.x;
    if (e >= E) return;
    int d = dst[e];
    int pos = atomicAdd(&cursor[d], 1);

    float fr[3]; int k0[3];
#pragma unroll
    for (int dd = 0; dd < 3; ++dd) {
        float p = attr[e * 3 + dd];
        p = fminf(fmaxf(p, 0.0f), 1.0f) * (float)(KSIZE - 1);
        float f0 = floorf(p);
        f0 = fminf(f0, (float)(KSIZE - 2));
        k0[dd] = (int)f0;
        fr[dd] = p - f0;
    }
    esrc[pos] = src[e];
    ewib[pos] = k0[0] * 25 + k0[1] * 5 + k0[2];

    float b[8];
#pragma unroll
    for (int t = 0; t < 8; ++t) {
        b[t] = ((t & 1) ? fr[0] : 1.0f - fr[0]) *
               (((t >> 1) & 1) ? fr[1] : 1.0f - fr[1]) *
               (((t >> 2) & 1) ? fr[2] : 1.0f - fr[2]);
    }
    float4* bp = (float4*)(ebasis + (size_t)pos * 8);
    bp[0] = make_float4(b[0], b[1], b[2], b[3]);
    bp[1] = make_float4(b[4], b[5], b[6], b[7]);
}

// Swizzled f16 weight table: Wh[wi*(Cin*Cout) + (i>>3)*(8*Cout) + (o^(wi&7))*8 + (i&7)]
// = W[wi][i][o].  16B rows per (wi, i-chunk, o) -> conflict-free ds_read_b128.
__global__ void prep_wh(const float* __restrict__ W, _Float16* __restrict__ Wh,
                        int Cin, int Cout) {
    int idx = blockIdx.x * blockDim.x + threadIdx.x;
    int tot = KTOT * Cin * Cout;
    if (idx >= tot) return;
    int wi = idx / (Cin * Cout);
    int r = idx % (Cin * Cout);
    int i = r / Cout, o = r % Cout;
    int op = o ^ (wi & 7);
    Wh[wi * (Cin * Cout) + (i >> 3) * (8 * Cout) + op * 8 + (i & 7)] = (_Float16)W[idx];
}

// ---------- fused gather layers, f16 weights in LDS ----------
// wave per node: 64 lanes = SLOTS edges x Cout channels.
template<int Cin, int Cout>
__global__ __launch_bounds__(512) void agg_f16(
        const int* __restrict__ rowptr, const int* __restrict__ esrc,
        const int* __restrict__ ewib, const float* __restrict__ ebasis,
        const float* __restrict__ x, const _Float16* __restrict__ Wg,
        const float* __restrict__ root, const float* __restrict__ bias,
        float* __restrict__ out, int N, int totalWaves) {
    constexpr int SLOTS = 64 / Cout;
    constexpr int WH = KTOT * Cin * Cout;
    __shared__ __align__(16) _Float16 Wl[WH];
    for (int t = threadIdx.x; t < WH / 8; t += 512)
        ((uint4*)Wl)[t] = ((const uint4*)Wg)[t];
    __syncthreads();

    const int lane = threadIdx.x & 63;
    const int o = lane & (Cout - 1);
    const int slot = lane / Cout;
    const int wid = blockIdx.x * 8 + (threadIdx.x >> 6);

    for (int v = wid; v < N; v += totalWaves) {
        const int beg = rowptr[v], end = rowptr[v + 1];
        float acc = 0.0f;
        for (int p0 = beg; p0 < end; p0 += SLOTS) {
            const int p = p0 + slot;
            const bool act = p < end;
            int s = 0, wib = 0;
            float bb[8];
#pragma unroll
            for (int t = 0; t < 8; ++t) bb[t] = 0.0f;
            if (act) {
                s = esrc[p];
                wib = ewib[p];
                const float4* bp = (const float4*)(ebasis + (size_t)p * 8);
                float4 q0 = bp[0], q1 = bp[1];
                bb[0] = q0.x; bb[1] = q0.y; bb[2] = q0.z; bb[3] = q0.w;
                bb[4] = q1.x; bb[5] = q1.y; bb[6] = q1.z; bb[7] = q1.w;
            }
            h2 hx[Cin / 2];
            const float4* xp = (const float4*)(x + (size_t)s * Cin);
#pragma unroll
            for (int c = 0; c < Cin / 4; ++c) {
                float4 q = xp[c];
                hx[2 * c]     = pack_f16(q.x, q.y);
                hx[2 * c + 1] = pack_f16(q.z, q.w);
            }
            constexpr int TAP[8] = {0, 25, 5, 30, 1, 26, 6, 31};
#pragma unroll
            for (int t = 0; t < 8; ++t) {
                const int wi = wib + TAP[t];
                const int op = o ^ (wi & 7);
                const int base = wi * (Cin * Cout) + op * 8;
                float dot = 0.0f;
#pragma unroll
                for (int c = 0; c < Cin / 8; ++c) {
                    union { uint4 u4; unsigned u[4]; } wu;
                    wu.u4 = *(const uint4*)(&Wl[base + c * (8 * Cout)]);
                    dot = fdot2f(hx[4 * c + 0], __builtin_bit_cast(h2, wu.u[0]), dot);
                    dot = fdot2f(hx[4 * c + 1], __builtin_bit_cast(h2, wu.u[1]), dot);
                    dot = fdot2f(hx[4 * c + 2], __builtin_bit_cast(h2, wu.u[2]), dot);
                    dot = fdot2f(hx[4 * c + 3], __builtin_bit_cast(h2, wu.u[3]), dot);
                }
                acc = fmaf(bb[t], dot, acc);
            }
        }
#pragma unroll
        for (int m = Cout; m < 64; m <<= 1) acc += __shfl_xor(acc, m);
        if (slot == 0) {
            float r = bias[o];
#pragma unroll
            for (int i = 0; i < Cin; ++i)
                r = fmaf(x[(size_t)v * Cin + i], root[i * Cout + o], r);
            float z = acc + r;
            out[(size_t)v * Cout + o] = z > 0.0f ? z : expm1f(z);
        }
    }
}

// Layer 1: Cin=1, Cout=8 — tiny W (4KB fp32, L1-cached), no LDS.
__global__ __launch_bounds__(512) void agg_l1(
        const int* __restrict__ rowptr, const int* __restrict__ esrc,
        const int* __restrict__ ewib, const float* __restrict__ ebasis,
        const float* __restrict__ x, const float* __restrict__ W,     // [125][8]
        const float* __restrict__ root, const float* __restrict__ bias,
        float* __restrict__ out, int N, int totalWaves) {
    const int lane = threadIdx.x & 63;
    const int o = lane & 7;
    const int slot = lane >> 3;
    const int wid = blockIdx.x * 8 + (threadIdx.x >> 6);

    for (int v = wid; v < N; v += totalWaves) {
        const int beg = rowptr[v], end = rowptr[v + 1];
        float acc = 0.0f;
        for (int p0 = beg; p0 < end; p0 += 8) {
            const int p = p0 + slot;
            const bool act = p < end;
            int wib = 0;
            float xv = 0.0f;
            float bb[8];
#pragma unroll
            for (int t = 0; t < 8; ++t) bb[t] = 0.0f;
            if (act) {
                xv = x[esrc[p]];
                wib = ewib[p];
                const float4* bp = (const float4*)(ebasis + (size_t)p * 8);
                float4 q0 = bp[0], q1 = bp[1];
                bb[0] = q0.x; bb[1] = q0.y; bb[2] = q0.z; bb[3] = q0.w;
                bb[4] = q1.x; bb[5] = q1.y; bb[6] = q1.z; bb[7] = q1.w;
            }
            constexpr int TAP[8] = {0, 25, 5, 30, 1, 26, 6, 31};
#pragma unroll
            for (int t = 0; t < 8; ++t) {
                const int wi = wib + TAP[t];
                acc = fmaf(bb[t] * xv, __ldg(&W[wi * 8 + o]), acc);
            }
        }
#pragma unroll
        for (int m = 8; m < 64; m <<= 1) acc += __shfl_xor(acc, m);
        if (slot == 0) {
            float z = acc + bias[o] + x[v] * root[o];
            out[(size_t)v * 8 + o] = z > 0.0f ? z : expm1f(z);
        }
    }
}

// Layer 5: Cin=8, Cout=1 — lane owns input channel; W native [125][8].
__global__ __launch_bounds__(512) void agg_l5(
        const int* __restrict__ rowptr, const int* __restrict__ esrc,
        const int* __restrict__ ewib, const float* __restrict__ ebasis,
        const float* __restrict__ x, const float* __restrict__ W,     // [125][8]
        const float* __restrict__ root, const float* __restrict__ bias,
        float* __restrict__ out, int N, int totalWaves) {
    const int lane = threadIdx.x & 63;
    const int i = lane & 7;
    const int slot = lane >> 3;
    const int wid = blockIdx.x * 8 + (threadIdx.x >> 6);

    for (int v = wid; v < N; v += totalWaves) {
        const int beg = rowptr[v], end = rowptr[v + 1];
        float acc = 0.0f;
        for (int p0 = beg; p0 < end; p0 += 8) {
            const int p = p0 + slot;
            const bool act = p < end;
            int wib = 0;
            float xi = 0.0f;
            float bb[8];
#pragma unroll
            for (int t = 0; t < 8; ++t) bb[t] = 0.0f;
            if (act) {
                xi = x[(size_t)esrc[p] * 8 + i];
                wib = ewib[p];
                const float4* bp = (const float4*)(ebasis + (size_t)p * 8);
                float4 q0 = bp[0], q1 = bp[1];
                bb[0] = q0.x; bb[1] = q0.y; bb[2] = q0.z; bb[3] = q0.w;
                bb[4] = q1.x; bb[5] = q1.y; bb[6] = q1.z; bb[7] = q1.w;
            }
            constexpr int TAP[8] = {0, 25, 5, 30, 1, 26, 6, 31};
#pragma unroll
            for (int t = 0; t < 8; ++t) {
                const int wi = wib + TAP[t];
                acc = fmaf(bb[t] * xi, __ldg(&W[wi * 8 + i]), acc);
            }
        }
        if (slot == 0) acc = fmaf(x[(size_t)v * 8 + i], root[i], acc);
#pragma unroll
        for (int m = 1; m < 64; m <<= 1) acc += __shfl_xor(acc, m);
        if (lane == 0) {
            float z = acc + bias[0];
            out[v] = z > 0.0f ? z : expm1f(z);
        }
    }
}

// ---------- host ----------

static inline char* align256(char* p) {
    return (char*)(((uintptr_t)p + 255) & ~(uintptr_t)255);
}

extern "C" void kernel_launch(void* const* d_in, const int* in_sizes, int n_in,
                              void* d_out, int out_size, void* d_ws, size_t ws_size,
                              hipStream_t stream) {
    const float* x    = (const float*)d_in[0];
    const int*   ei   = (const int*)d_in[1];
    const float* attr = (const float*)d_in[2];
    const float* w[5]    = {(const float*)d_in[3],  (const float*)d_in[6],
                            (const float*)d_in[9],  (const float*)d_in[12],
                            (const float*)d_in[15]};
    const float* root[5] = {(const float*)d_in[4],  (const float*)d_in[7],
                            (const float*)d_in[10], (const float*)d_in[13],
                            (const float*)d_in[16]};
    const float* bias[5] = {(const float*)d_in[5],  (const float*)d_in[8],
                            (const float*)d_in[11], (const float*)d_in[14],
                            (const float*)d_in[17]};

    const int N = in_sizes[0];
    const int E = in_sizes[1] / 2;
    const int* src = ei;
    const int* dst = ei + E;

    char* ws = (char*)d_ws;
    float* bufA   = (float*)ws;  ws = align256(ws + (size_t)N * 16 * 4);
    float* bufB   = (float*)ws;  ws = align256(ws + (size_t)N * 16 * 4);
    int*   counts = (int*)ws;    ws = align256(ws + (size_t)N * 4);
    int*   cursor = (int*)ws;    ws = align256(ws + (size_t)N * 4);
    int*   rowptr = (int*)ws;    ws = align256(ws + (size_t)(N + 1) * 4);
    int*   bsums  = (int*)ws;    ws = align256(ws + 256 * 4);
    int*   esrc   = (int*)ws;    ws = align256(ws + (size_t)E * 4);
    int*   ewib   = (int*)ws;    ws = align256(ws + (size_t)E * 4);
    float* ebasis = (float*)ws;  ws = align256(ws + (size_t)E * 8 * 4);
    _Float16* wh2 = (_Float16*)ws; ws = align256(ws + (size_t)KTOT * 8 * 16 * 2);
    _Float16* wh3 = (_Float16*)ws; ws = align256(ws + (size_t)KTOT * 16 * 16 * 2);
    _Float16* wh4 = (_Float16*)ws; ws = align256(ws + (size_t)KTOT * 16 * 8 * 2);

    const int B = 256;
    const int nb = cdiv(N, 256);

    // CSR build
    zero_int<<<cdiv(N, B), B, 0, stream>>>(counts, N);
    hist_kernel<<<cdiv(E, B), B, 0, stream>>>(dst, counts, E);
    scan_blocks<<<nb, 256, 0, stream>>>(counts, rowptr, bsums, N);
    scan_sums<<<1, 256, 0, stream>>>(bsums, nb);
    add_offsets<<<nb, 256, 0, stream>>>(rowptr, bsums, cursor, N, E);
    build_edges<<<cdiv(E, B), B, 0, stream>>>(src, dst, attr, cursor,
                                              esrc, ewib, ebasis, E);

    // f16 swizzled weight tables for the LDS layers
    prep_wh<<<cdiv(KTOT * 8 * 16, B), B, 0, stream>>>(w[1], wh2, 8, 16);
    prep_wh<<<cdiv(KTOT * 16 * 16, B), B, 0, stream>>>(w[2], wh3, 16, 16);
    prep_wh<<<cdiv(KTOT * 16 * 8, B), B, 0, stream>>>(w[3], wh4, 16, 8);

    transform_kernel<<<cdiv(N, B), B, 0, stream>>>(x, bufA, N);

    const int GB = 512;            // blocks for agg kernels
    const int TW = GB * 8;         // total waves

    agg_l1<<<GB, 512, 0, stream>>>(rowptr, esrc, ewib, ebasis, bufA, w[0],
                                   root[0], bias[0], bufB, N, TW);
    agg_f16<8, 16><<<GB, 512, 0, stream>>>(rowptr, esrc, ewib, ebasis, bufB, wh2,
                                           root[1], bias[1], bufA, N, TW);
    agg_f16<16, 16><<<GB, 512, 0, stream>>>(rowptr, esrc, ewib, ebasis, bufA, wh3,
                                            root[2], bias[2], bufB, N, TW);
    agg_f16<16, 8><<<GB, 512, 0, stream>>>(rowptr, esrc, ewib, ebasis, bufB, wh4,
                                           root[3], bias[3], bufA, N, TW);
    agg_l5<<<GB, 512, 0, stream>>>(rowptr, esrc, ewib, ebasis, bufA, w[4],
                                   root[4], bias[4], (float*)d_out, N, TW);
}